// Round 8
// baseline (223.751 us; speedup 1.0000x reference)
//
#include <hip/hip_runtime.h>
#include <math.h>

// GCN 2-layer, N=100K, E=3.2M, feat 1->16->2, log_softmax.
//
// R7 lessons (rocprof): (1) place at EPT=16384 -> only 196 blocks < 256 CUs,
// occupancy 12%, latency-bound 58us. (2) Agg kernels ~45us each: dependent
// load->gather->LDS-atomic chain, no unroll, 512 threads. Inner loop, not
// metadata, is the cost.
// R8: EPT=8192 (391 blocks) + int4 vector loads in hist/place; payload split
// into wq[] = (w_bits & ~0xFF) | dstLow (dstLow in w's low mantissa bits,
// 2^-17 self-consistent perturbation) and sr[] = src, so the deg pass reads
// 13MB not 26MB; agg kernels use 1024 threads + manual 4x unroll (batched
// independent loads -> batched gathers -> batched LDS atomics).
// Algebra: layer1 rank-1 (scalar per node); 2-class log_softmax needs only
// d = a1-a0 (scalar gd per node); dinv[dst] factored into epilogues.

static constexpr int BS        = 512;    // sort-phase block size
static constexpr int BSA       = 1024;   // aggregation block size
static constexpr int CHUNK     = 256;    // nodes per bucket (pow2)
static constexpr int LOG_CHUNK = 8;
static constexpr int MAXNB     = 512;    // max buckets (N <= 131072)
static constexpr int EPT       = 8192;   // edges per sort tile (16/thread)

// ======================= sort phase =======================

__global__ __launch_bounds__(BS) void zero_cnt_kernel(unsigned int* __restrict__ cnt,
                                                      int nb) {
    int t = threadIdx.x;
    if (t < nb) cnt[t] = 0u;
}

__global__ __launch_bounds__(BS) void hist_kernel(const int* __restrict__ dst,
                                                  unsigned int* __restrict__ cnt,
                                                  int E, int nb) {
    __shared__ unsigned int h[MAXNB];
    const int t = threadIdx.x;
    for (int i = t; i < nb; i += BS) h[i] = 0u;
    __syncthreads();
    const int base = blockIdx.x * EPT;
    const int nE   = min(EPT, E - base);
    if (nE == EPT) {
        const int4* d4 = (const int4*)(dst + base);
#pragma unroll
        for (int j = 0; j < EPT / (BS * 4); ++j) {
            int4 v = d4[t + j * BS];
            atomicAdd(&h[(unsigned int)v.x >> LOG_CHUNK], 1u);
            atomicAdd(&h[(unsigned int)v.y >> LOG_CHUNK], 1u);
            atomicAdd(&h[(unsigned int)v.z >> LOG_CHUNK], 1u);
            atomicAdd(&h[(unsigned int)v.w >> LOG_CHUNK], 1u);
        }
    } else {
        for (int k = t; k < nE; k += BS)
            atomicAdd(&h[(unsigned int)dst[base + k] >> LOG_CHUNK], 1u);
    }
    __syncthreads();
    for (int i = t; i < nb; i += BS) {
        unsigned int c = h[i];
        if (c) atomicAdd(&cnt[i], c);
    }
}

__global__ __launch_bounds__(BS) void scan_kernel(const unsigned int* __restrict__ cnt,
                                                  unsigned int* __restrict__ start,   // nb+1
                                                  unsigned int* __restrict__ cursor,  // nb
                                                  int nb) {
    __shared__ unsigned int s[MAXNB];
    const int t = threadIdx.x;
    unsigned int c = (t < nb) ? cnt[t] : 0u;
    s[t] = c;
    __syncthreads();
    for (int off = 1; off < MAXNB; off <<= 1) {
        unsigned int v = (t >= off) ? s[t - off] : 0u;
        __syncthreads();
        s[t] += v;
        __syncthreads();
    }
    if (t < nb) { start[t + 1] = s[t]; cursor[t] = s[t] - c; }
    if (t == 0) start[0] = 0u;
}

__global__ __launch_bounds__(BS) void place_kernel(
    const int* __restrict__ src, const int* __restrict__ dst,
    const float* __restrict__ w,
    unsigned int* __restrict__ cursor,    // [nb] global bump cursors
    unsigned int* __restrict__ wq,        // [E] (w_bits & ~0xFF) | dstLow
    unsigned int* __restrict__ sr,        // [E] src index
    int E, int nb) {
    __shared__ unsigned int h[MAXNB];
    __shared__ unsigned int lcur[MAXNB];
    const int base = blockIdx.x * EPT;
    const int nE   = min(EPT, E - base);
    const int t    = threadIdx.x;
    for (int i = t; i < nb; i += BS) h[i] = 0u;
    __syncthreads();
    int dreg[EPT / BS];                   // 16 dsts cached in regs
    if (nE == EPT) {
        const int4* d4 = (const int4*)(dst + base);
#pragma unroll
        for (int j = 0; j < EPT / (BS * 4); ++j) {
            int4 v = d4[t + j * BS];
            dreg[4 * j + 0] = v.x; dreg[4 * j + 1] = v.y;
            dreg[4 * j + 2] = v.z; dreg[4 * j + 3] = v.w;
            atomicAdd(&h[(unsigned int)v.x >> LOG_CHUNK], 1u);
            atomicAdd(&h[(unsigned int)v.y >> LOG_CHUNK], 1u);
            atomicAdd(&h[(unsigned int)v.z >> LOG_CHUNK], 1u);
            atomicAdd(&h[(unsigned int)v.w >> LOG_CHUNK], 1u);
        }
    } else {
        int c = 0;
        for (int k = t; k < nE; k += BS) {
            int d = dst[base + k];
            dreg[c++] = d;
            atomicAdd(&h[(unsigned int)d >> LOG_CHUNK], 1u);
        }
    }
    __syncthreads();
    for (int i = t; i < nb; i += BS) {
        unsigned int c = h[i];
        lcur[i] = c ? atomicAdd(&cursor[i], c) : 0u;   // reserve global run
    }
    __syncthreads();
    if (nE == EPT) {
        const int4*   s4 = (const int4*)(src + base);
        const float4* w4 = (const float4*)(w + base);
#pragma unroll
        for (int j = 0; j < EPT / (BS * 4); ++j) {
            int4   sv = s4[t + j * BS];
            float4 wv = w4[t + j * BS];
            int dd; unsigned int slot;
#define PLACE_ONE(M, WF, SF)                                              \
            dd   = dreg[4 * j + M];                                       \
            slot = atomicAdd(&lcur[(unsigned int)dd >> LOG_CHUNK], 1u);   \
            wq[slot] = (__float_as_uint(WF) & 0xFFFFFF00u) |              \
                       (unsigned int)(dd & (CHUNK - 1));                  \
            sr[slot] = (unsigned int)(SF);
            PLACE_ONE(0, wv.x, sv.x)
            PLACE_ONE(1, wv.y, sv.y)
            PLACE_ONE(2, wv.z, sv.z)
            PLACE_ONE(3, wv.w, sv.w)
#undef PLACE_ONE
        }
    } else {
        int c = 0;
        for (int k = t; k < nE; k += BS) {
            int e = base + k;
            int dd = dreg[c++];
            unsigned int slot = atomicAdd(&lcur[(unsigned int)dd >> LOG_CHUNK], 1u);
            wq[slot] = (__float_as_uint(w[e]) & 0xFFFFFF00u) |
                       (unsigned int)(dd & (CHUNK - 1));
            sr[slot] = (unsigned int)src[e];
        }
    }
}

// ======================= aggregation phase =======================

__global__ __launch_bounds__(BSA) void deg_dinv_kernel(
    const unsigned int* __restrict__ wq,
    const unsigned int* __restrict__ start,
    const float* __restrict__ x,
    float* __restrict__ dinv, float* __restrict__ xd, int N) {
    __shared__ float acc[CHUNK];
    const int b = blockIdx.x, t = threadIdx.x;
    if (t < CHUNK) acc[t] = 0.0f;
    __syncthreads();
    const unsigned int s0 = start[b], s1 = start[b + 1];
    unsigned int i = s0 + t;
    for (; i + 3u * BSA < s1; i += 4u * BSA) {
        unsigned int q0 = wq[i], q1 = wq[i + BSA], q2 = wq[i + 2 * BSA], q3 = wq[i + 3 * BSA];
        atomicAdd(&acc[q0 & (CHUNK - 1)], __uint_as_float(q0 & 0xFFFFFF00u));
        atomicAdd(&acc[q1 & (CHUNK - 1)], __uint_as_float(q1 & 0xFFFFFF00u));
        atomicAdd(&acc[q2 & (CHUNK - 1)], __uint_as_float(q2 & 0xFFFFFF00u));
        atomicAdd(&acc[q3 & (CHUNK - 1)], __uint_as_float(q3 & 0xFFFFFF00u));
    }
    for (; i < s1; i += BSA) {
        unsigned int q = wq[i];
        atomicAdd(&acc[q & (CHUNK - 1)], __uint_as_float(q & 0xFFFFFF00u));
    }
    __syncthreads();
    int n = b * CHUNK + t;
    if (t < CHUNK && n < N) {
        float d = acc[t] + 1.0f;                 // self-loop fill 1.0
        float r = (d > 0.0f) ? rsqrtf(d) : 0.0f;
        dinv[n] = r;
        xd[n]   = r * x[n];
    }
}

__global__ __launch_bounds__(BSA) void s_gamma_kernel(
    const unsigned int* __restrict__ wq,
    const unsigned int* __restrict__ sr,
    const unsigned int* __restrict__ start,
    const float* __restrict__ dinv,
    const float* __restrict__ xd,
    const float* __restrict__ W1,    // [16]
    const float* __restrict__ b1,    // [16]
    const float* __restrict__ W2,    // [16][2]
    float* __restrict__ gd, int N) {
    __shared__ float acc[CHUNK];
    const int b = blockIdx.x, t = threadIdx.x;
    if (t < CHUNK) acc[t] = 0.0f;
    __syncthreads();
    const unsigned int s0 = start[b], s1 = start[b + 1];
    unsigned int i = s0 + t;
    for (; i + 3u * BSA < s1; i += 4u * BSA) {
        unsigned int q0 = wq[i], q1 = wq[i + BSA], q2 = wq[i + 2 * BSA], q3 = wq[i + 3 * BSA];
        unsigned int r0 = sr[i], r1 = sr[i + BSA], r2 = sr[i + 2 * BSA], r3 = sr[i + 3 * BSA];
        float x0 = xd[r0], x1 = xd[r1], x2 = xd[r2], x3 = xd[r3];
        atomicAdd(&acc[q0 & (CHUNK - 1)], __uint_as_float(q0 & 0xFFFFFF00u) * x0);
        atomicAdd(&acc[q1 & (CHUNK - 1)], __uint_as_float(q1 & 0xFFFFFF00u) * x1);
        atomicAdd(&acc[q2 & (CHUNK - 1)], __uint_as_float(q2 & 0xFFFFFF00u) * x2);
        atomicAdd(&acc[q3 & (CHUNK - 1)], __uint_as_float(q3 & 0xFFFFFF00u) * x3);
    }
    for (; i < s1; i += BSA) {
        unsigned int q = wq[i];
        atomicAdd(&acc[q & (CHUNK - 1)], __uint_as_float(q & 0xFFFFFF00u) * xd[sr[i]]);
    }
    __syncthreads();
    int n = b * CHUNK + t;
    if (t < CHUNK && n < N) {
        float dv = dinv[n];
        float sv = dv * (acc[t] + xd[n]);        // + self-loop dv*dv*x[n]
        float g = 0.0f;
#pragma unroll
        for (int f = 0; f < 16; ++f) {
            float h = fmaxf(sv * W1[f] + b1[f], 0.0f);     // relu(layer1)
            g += h * (W2[2 * f + 1] - W2[2 * f + 0]);      // gamma = g1-g0
        }
        gd[n] = dv * g;                          // pre-scaled for layer 2
    }
}

__global__ __launch_bounds__(BSA) void d_out_kernel(
    const unsigned int* __restrict__ wq,
    const unsigned int* __restrict__ sr,
    const unsigned int* __restrict__ start,
    const float* __restrict__ dinv,
    const float* __restrict__ gd,
    const float* __restrict__ b2,    // [2]
    float* __restrict__ out, int N) {
    __shared__ float acc[CHUNK];
    const int b = blockIdx.x, t = threadIdx.x;
    if (t < CHUNK) acc[t] = 0.0f;
    __syncthreads();
    const unsigned int s0 = start[b], s1 = start[b + 1];
    unsigned int i = s0 + t;
    for (; i + 3u * BSA < s1; i += 4u * BSA) {
        unsigned int q0 = wq[i], q1 = wq[i + BSA], q2 = wq[i + 2 * BSA], q3 = wq[i + 3 * BSA];
        unsigned int r0 = sr[i], r1 = sr[i + BSA], r2 = sr[i + 2 * BSA], r3 = sr[i + 3 * BSA];
        float g0 = gd[r0], g1 = gd[r1], g2 = gd[r2], g3 = gd[r3];
        atomicAdd(&acc[q0 & (CHUNK - 1)], __uint_as_float(q0 & 0xFFFFFF00u) * g0);
        atomicAdd(&acc[q1 & (CHUNK - 1)], __uint_as_float(q1 & 0xFFFFFF00u) * g1);
        atomicAdd(&acc[q2 & (CHUNK - 1)], __uint_as_float(q2 & 0xFFFFFF00u) * g2);
        atomicAdd(&acc[q3 & (CHUNK - 1)], __uint_as_float(q3 & 0xFFFFFF00u) * g3);
    }
    for (; i < s1; i += BSA) {
        unsigned int q = wq[i];
        atomicAdd(&acc[q & (CHUNK - 1)], __uint_as_float(q & 0xFFFFFF00u) * gd[sr[i]]);
    }
    __syncthreads();
    int n = b * CHUNK + t;
    if (t < CHUNK && n < N) {
        float dv = dinv[n];
        float d = dv * (acc[t] + gd[n]) + (b2[1] - b2[0]);
        float lse = fmaxf(d, 0.0f) + log1pf(expf(-fabsf(d)));   // log(1+e^d)
        out[2 * n + 0] = -lse;
        out[2 * n + 1] = d - lse;
    }
}

// ======================= fallback: R3 global-atomic path =======================

static constexpr int BLOCK = 256;

__global__ void zero_kernel(float* __restrict__ a, float* __restrict__ b, int n2) {
    int i = blockIdx.x * blockDim.x + threadIdx.x;
    if (i < n2) { a[i] = 0.0f; b[i] = 0.0f; }
}
__global__ void deg_kernel(const int* __restrict__ dst, const float* __restrict__ w,
                           float* __restrict__ deg, int E) {
    int e = blockIdx.x * blockDim.x + threadIdx.x;
    if (e < E) atomicAdd(&deg[dst[e]], w[e]);
}
__global__ void dinv_kernel(float* __restrict__ deg, int N) {
    int n = blockIdx.x * blockDim.x + threadIdx.x;
    if (n < N) {
        float d = deg[n] + 1.0f;
        deg[n] = (d > 0.0f) ? rsqrtf(d) : 0.0f;
    }
}
__global__ void s_kernel(const int* __restrict__ src, const int* __restrict__ dst,
                         const float* __restrict__ w, const float* __restrict__ dinv,
                         const float* __restrict__ x, float* __restrict__ s, int E) {
    int e = blockIdx.x * blockDim.x + threadIdx.x;
    if (e < E) {
        int si = src[e], di = dst[e];
        atomicAdd(&s[di], dinv[si] * w[e] * dinv[di] * x[si]);
    }
}
__global__ void g_kernel(const float* __restrict__ s, const float* __restrict__ dinv,
                         const float* __restrict__ x, const float* __restrict__ W1,
                         const float* __restrict__ b1, const float* __restrict__ W2,
                         float2* __restrict__ g, int N) {
    int n = blockIdx.x * blockDim.x + threadIdx.x;
    if (n < N) {
        float dv = dinv[n];
        float sv = s[n] + dv * dv * x[n];
        float g0 = 0.0f, g1 = 0.0f;
#pragma unroll
        for (int f = 0; f < 16; ++f) {
            float h = fmaxf(sv * W1[f] + b1[f], 0.0f);
            g0 += h * W2[2 * f + 0];
            g1 += h * W2[2 * f + 1];
        }
        g[n] = make_float2(g0, g1);
    }
}
__global__ void agg2_kernel(const int* __restrict__ src, const int* __restrict__ dst,
                            const float* __restrict__ w, const float* __restrict__ dinv,
                            const float2* __restrict__ g, float* __restrict__ agg, int E) {
    int e = blockIdx.x * blockDim.x + threadIdx.x;
    if (e < E) {
        int si = src[e], di = dst[e];
        float norm = dinv[si] * w[e] * dinv[di];
        float2 gv = g[si];
        atomicAdd(&agg[2 * di + 0], norm * gv.x);
        atomicAdd(&agg[2 * di + 1], norm * gv.y);
    }
}
__global__ void out_kernel(float* __restrict__ out, const float* __restrict__ dinv,
                           const float2* __restrict__ g, const float* __restrict__ b2, int N) {
    int n = blockIdx.x * blockDim.x + threadIdx.x;
    if (n < N) {
        float dv2 = dinv[n] * dinv[n];
        float2 gv = g[n];
        float a0 = out[2 * n + 0] + dv2 * gv.x + b2[0];
        float a1 = out[2 * n + 1] + dv2 * gv.y + b2[1];
        float m = fmaxf(a0, a1);
        float lse = m + logf(expf(a0 - m) + expf(a1 - m));
        out[2 * n + 0] = a0 - lse;
        out[2 * n + 1] = a1 - lse;
    }
}

// ======================= launch =======================

extern "C" void kernel_launch(void* const* d_in, const int* in_sizes, int n_in,
                              void* d_out, int out_size, void* d_ws, size_t ws_size,
                              hipStream_t stream) {
    const float* x  = (const float*)d_in[0];
    const int*   ei = (const int*)d_in[1];     // [2, E] delivered as int32
    const float* w  = (const float*)d_in[2];
    const float* W1 = (const float*)d_in[3];
    const float* b1 = (const float*)d_in[4];
    const float* W2 = (const float*)d_in[5];
    const float* b2 = (const float*)d_in[6];
    float* out = (float*)d_out;

    const int N = in_sizes[0];
    const int E = in_sizes[2];
    const int* src = ei;
    const int* dst = ei + E;

    const int nb = (N + CHUNK - 1) / CHUNK;    // 391

    // ws layout: wq | sr | cnt | start | cursor | dinv | xd | gd
    size_t off = 0;
    size_t wq_off     = off;  off += (size_t)E * 4;
    size_t sr_off     = off;  off += (size_t)E * 4;
    size_t cnt_off    = off;  off += (size_t)nb * 4;
    size_t start_off  = off;  off += (size_t)(nb + 1) * 4;
    size_t cursor_off = off;  off += (size_t)nb * 4;
    size_t dinv_off   = off;  off += (size_t)N * 4;
    size_t xd_off     = off;  off += (size_t)N * 4;
    size_t gd_off     = off;  off += (size_t)N * 4;
    const size_t required = off;

    if (nb <= MAXNB && ws_size >= required) {
        char* wsb = (char*)d_ws;
        unsigned int* wq     = (unsigned int*)(wsb + wq_off);
        unsigned int* sr     = (unsigned int*)(wsb + sr_off);
        unsigned int* cnt    = (unsigned int*)(wsb + cnt_off);
        unsigned int* startp = (unsigned int*)(wsb + start_off);
        unsigned int* cursor = (unsigned int*)(wsb + cursor_off);
        float* dinv = (float*)(wsb + dinv_off);
        float* xd   = (float*)(wsb + xd_off);
        float* gd   = (float*)(wsb + gd_off);

        const int gridT = (E + EPT - 1) / EPT;     // 391

        zero_cnt_kernel<<<1,     BS,  0, stream>>>(cnt, nb);
        hist_kernel    <<<gridT, BS,  0, stream>>>(dst, cnt, E, nb);
        scan_kernel    <<<1,     BS,  0, stream>>>(cnt, startp, cursor, nb);
        place_kernel   <<<gridT, BS,  0, stream>>>(src, dst, w, cursor, wq, sr, E, nb);
        deg_dinv_kernel<<<nb,    BSA, 0, stream>>>(wq, startp, x, dinv, xd, N);
        s_gamma_kernel <<<nb,    BSA, 0, stream>>>(wq, sr, startp, dinv, xd, W1, b1, W2, gd, N);
        d_out_kernel   <<<nb,    BSA, 0, stream>>>(wq, sr, startp, dinv, gd, b2, out, N);
    } else {
        // R3 fallback: global-atomic path (needs 4N floats of ws)
        float*  ws   = (float*)d_ws;
        float*  dinv = ws;
        float*  s    = ws + (size_t)N;
        float2* g    = (float2*)(ws + (size_t)2 * N);
        const int gridE  = (E + BLOCK - 1) / BLOCK;
        const int gridN  = (N + BLOCK - 1) / BLOCK;
        const int gridN2 = (2 * N + BLOCK - 1) / BLOCK;
        zero_kernel<<<gridN2, BLOCK, 0, stream>>>(ws, out, 2 * N);
        deg_kernel <<<gridE,  BLOCK, 0, stream>>>(dst, w, dinv, E);
        dinv_kernel<<<gridN,  BLOCK, 0, stream>>>(dinv, N);
        s_kernel   <<<gridE,  BLOCK, 0, stream>>>(src, dst, w, dinv, x, s, E);
        g_kernel   <<<gridN,  BLOCK, 0, stream>>>(s, dinv, x, W1, b1, W2, g, N);
        agg2_kernel<<<gridE,  BLOCK, 0, stream>>>(src, dst, w, dinv, g, out, E);
        out_kernel <<<gridN,  BLOCK, 0, stream>>>(out, dinv, g, b2, N);
    }
}

// Round 9
// 201.813 us; speedup vs baseline: 1.1087x; 1.1087x over previous
//
#include <hip/hip_runtime.h>
#include <math.h>

// GCN 2-layer, N=100K, E=3.2M, feat 1->16->2, log_softmax.
//
// R8 lesson (rocprof): splitting payload into two 4B arrays halved per-run
// byte density -> 4.3x write amplification (112 MB). R7's single-u64 write
// path was already near the line-granularity floor (measured 35 MB ~= model).
// R7's actual problem: 196 blocks < 256 CUs, 2 waves/SIMD -> latency-bound.
// R9: single u64 payload (w<<32|src<<8|dstLow), EPT=12288 @ BS=1024
// -> 261 blocks, 4 waves/SIMD; int4 vector loads; agg keeps 1024-thread
// 4x-unrolled batched loads->gathers->LDS atomics, reading u64 payload.
// Algebra: layer1 rank-1 (scalar s per node); 2-class log_softmax needs only
// d = a1-a0 (scalar gd per node); dinv[dst] factored into epilogues.

static constexpr int BS        = 1024;   // sort-phase block size
static constexpr int BSA       = 1024;   // aggregation block size
static constexpr int CHUNK     = 256;    // nodes per bucket (pow2)
static constexpr int LOG_CHUNK = 8;
static constexpr int MAXNB     = 512;    // max buckets (N <= 131072)
static constexpr int EPT       = 12288;  // edges per sort tile (12/thread)

// ======================= sort phase =======================

__global__ __launch_bounds__(BS) void zero_cnt_kernel(unsigned int* __restrict__ cnt,
                                                      int nb) {
    int t = threadIdx.x;
    if (t < nb) cnt[t] = 0u;
}

__global__ __launch_bounds__(BS) void hist_kernel(const int* __restrict__ dst,
                                                  unsigned int* __restrict__ cnt,
                                                  int E, int nb) {
    __shared__ unsigned int h[MAXNB];
    const int t = threadIdx.x;
    for (int i = t; i < nb; i += BS) h[i] = 0u;
    __syncthreads();
    const int base = blockIdx.x * EPT;
    const int nE   = min(EPT, E - base);
    if (nE == EPT) {
        const int4* d4 = (const int4*)(dst + base);
#pragma unroll
        for (int j = 0; j < EPT / (BS * 4); ++j) {
            int4 v = d4[t + j * BS];
            atomicAdd(&h[(unsigned int)v.x >> LOG_CHUNK], 1u);
            atomicAdd(&h[(unsigned int)v.y >> LOG_CHUNK], 1u);
            atomicAdd(&h[(unsigned int)v.z >> LOG_CHUNK], 1u);
            atomicAdd(&h[(unsigned int)v.w >> LOG_CHUNK], 1u);
        }
    } else {
        for (int k = t; k < nE; k += BS)
            atomicAdd(&h[(unsigned int)dst[base + k] >> LOG_CHUNK], 1u);
    }
    __syncthreads();
    for (int i = t; i < nb; i += BS) {
        unsigned int c = h[i];
        if (c) atomicAdd(&cnt[i], c);
    }
}

__global__ __launch_bounds__(512) void scan_kernel(const unsigned int* __restrict__ cnt,
                                                   unsigned int* __restrict__ start,   // nb+1
                                                   unsigned int* __restrict__ cursor,  // nb
                                                   int nb) {
    __shared__ unsigned int s[MAXNB];
    const int t = threadIdx.x;
    unsigned int c = (t < nb) ? cnt[t] : 0u;
    s[t] = c;
    __syncthreads();
    for (int off = 1; off < MAXNB; off <<= 1) {
        unsigned int v = (t >= off) ? s[t - off] : 0u;
        __syncthreads();
        s[t] += v;
        __syncthreads();
    }
    if (t < nb) { start[t + 1] = s[t]; cursor[t] = s[t] - c; }
    if (t == 0) start[0] = 0u;
}

__global__ __launch_bounds__(BS) void place_kernel(
    const int* __restrict__ src, const int* __restrict__ dst,
    const float* __restrict__ w,
    unsigned int* __restrict__ cursor,           // [nb] global bump cursors
    unsigned long long* __restrict__ payload,    // [E] bucket-contiguous
    int E, int nb) {
    __shared__ unsigned int h[MAXNB];
    __shared__ unsigned int lcur[MAXNB];
    const int base = blockIdx.x * EPT;
    const int nE   = min(EPT, E - base);
    const int t    = threadIdx.x;
    for (int i = t; i < nb; i += BS) h[i] = 0u;
    __syncthreads();
    int dreg[EPT / BS];                           // 12 dsts cached in regs
    if (nE == EPT) {
        const int4* d4 = (const int4*)(dst + base);
#pragma unroll
        for (int j = 0; j < EPT / (BS * 4); ++j) {
            int4 v = d4[t + j * BS];
            dreg[4 * j + 0] = v.x; dreg[4 * j + 1] = v.y;
            dreg[4 * j + 2] = v.z; dreg[4 * j + 3] = v.w;
            atomicAdd(&h[(unsigned int)v.x >> LOG_CHUNK], 1u);
            atomicAdd(&h[(unsigned int)v.y >> LOG_CHUNK], 1u);
            atomicAdd(&h[(unsigned int)v.z >> LOG_CHUNK], 1u);
            atomicAdd(&h[(unsigned int)v.w >> LOG_CHUNK], 1u);
        }
    } else {
        int c = 0;
        for (int k = t; k < nE; k += BS) {
            int d = dst[base + k];
            dreg[c++] = d;
            atomicAdd(&h[(unsigned int)d >> LOG_CHUNK], 1u);
        }
    }
    __syncthreads();
    for (int i = t; i < nb; i += BS) {
        unsigned int c = h[i];
        lcur[i] = c ? atomicAdd(&cursor[i], c) : 0u;   // reserve global run
    }
    __syncthreads();
    if (nE == EPT) {
        const int4*   s4 = (const int4*)(src + base);
        const float4* w4 = (const float4*)(w + base);
#pragma unroll
        for (int j = 0; j < EPT / (BS * 4); ++j) {
            int4   sv = s4[t + j * BS];
            float4 wv = w4[t + j * BS];
#define PLACE_ONE(M, WF, SF) {                                               \
            int dd = dreg[4 * j + M];                                        \
            unsigned int slot =                                              \
                atomicAdd(&lcur[(unsigned int)dd >> LOG_CHUNK], 1u);         \
            payload[slot] =                                                  \
                ((unsigned long long)__float_as_uint(WF) << 32) |            \
                ((unsigned int)(SF) << LOG_CHUNK) |                          \
                (unsigned int)(dd & (CHUNK - 1)); }
            PLACE_ONE(0, wv.x, sv.x)
            PLACE_ONE(1, wv.y, sv.y)
            PLACE_ONE(2, wv.z, sv.z)
            PLACE_ONE(3, wv.w, sv.w)
#undef PLACE_ONE
        }
    } else {
        int c = 0;
        for (int k = t; k < nE; k += BS) {
            int e = base + k;
            int dd = dreg[c++];
            unsigned int slot = atomicAdd(&lcur[(unsigned int)dd >> LOG_CHUNK], 1u);
            payload[slot] =
                ((unsigned long long)__float_as_uint(w[e]) << 32) |
                ((unsigned int)src[e] << LOG_CHUNK) |
                (unsigned int)(dd & (CHUNK - 1));
        }
    }
}

// ======================= aggregation phase =======================

__global__ __launch_bounds__(BSA) void deg_dinv_kernel(
    const unsigned long long* __restrict__ payload,
    const unsigned int* __restrict__ start,
    const float* __restrict__ x,
    float* __restrict__ dinv, float* __restrict__ xd, int N) {
    __shared__ float acc[CHUNK];
    const int b = blockIdx.x, t = threadIdx.x;
    if (t < CHUNK) acc[t] = 0.0f;
    __syncthreads();
    const unsigned int s0 = start[b], s1 = start[b + 1];
    unsigned int i = s0 + t;
    for (; i + 3u * BSA < s1; i += 4u * BSA) {
        unsigned long long p0 = payload[i],           p1 = payload[i + BSA];
        unsigned long long p2 = payload[i + 2 * BSA], p3 = payload[i + 3 * BSA];
        atomicAdd(&acc[(unsigned int)p0 & (CHUNK - 1)], __uint_as_float((unsigned int)(p0 >> 32)));
        atomicAdd(&acc[(unsigned int)p1 & (CHUNK - 1)], __uint_as_float((unsigned int)(p1 >> 32)));
        atomicAdd(&acc[(unsigned int)p2 & (CHUNK - 1)], __uint_as_float((unsigned int)(p2 >> 32)));
        atomicAdd(&acc[(unsigned int)p3 & (CHUNK - 1)], __uint_as_float((unsigned int)(p3 >> 32)));
    }
    for (; i < s1; i += BSA) {
        unsigned long long p = payload[i];
        atomicAdd(&acc[(unsigned int)p & (CHUNK - 1)], __uint_as_float((unsigned int)(p >> 32)));
    }
    __syncthreads();
    int n = b * CHUNK + t;
    if (t < CHUNK && n < N) {
        float d = acc[t] + 1.0f;                 // self-loop fill 1.0
        float r = (d > 0.0f) ? rsqrtf(d) : 0.0f;
        dinv[n] = r;
        xd[n]   = r * x[n];
    }
}

__global__ __launch_bounds__(BSA) void s_gamma_kernel(
    const unsigned long long* __restrict__ payload,
    const unsigned int* __restrict__ start,
    const float* __restrict__ dinv,
    const float* __restrict__ xd,
    const float* __restrict__ W1,    // [16]
    const float* __restrict__ b1,    // [16]
    const float* __restrict__ W2,    // [16][2]
    float* __restrict__ gd, int N) {
    __shared__ float acc[CHUNK];
    const int b = blockIdx.x, t = threadIdx.x;
    if (t < CHUNK) acc[t] = 0.0f;
    __syncthreads();
    const unsigned int s0 = start[b], s1 = start[b + 1];
    unsigned int i = s0 + t;
    for (; i + 3u * BSA < s1; i += 4u * BSA) {
        unsigned long long p0 = payload[i],           p1 = payload[i + BSA];
        unsigned long long p2 = payload[i + 2 * BSA], p3 = payload[i + 3 * BSA];
        float x0 = xd[((unsigned int)p0 >> LOG_CHUNK) & 0xFFFFFFu];
        float x1 = xd[((unsigned int)p1 >> LOG_CHUNK) & 0xFFFFFFu];
        float x2 = xd[((unsigned int)p2 >> LOG_CHUNK) & 0xFFFFFFu];
        float x3 = xd[((unsigned int)p3 >> LOG_CHUNK) & 0xFFFFFFu];
        atomicAdd(&acc[(unsigned int)p0 & (CHUNK - 1)], __uint_as_float((unsigned int)(p0 >> 32)) * x0);
        atomicAdd(&acc[(unsigned int)p1 & (CHUNK - 1)], __uint_as_float((unsigned int)(p1 >> 32)) * x1);
        atomicAdd(&acc[(unsigned int)p2 & (CHUNK - 1)], __uint_as_float((unsigned int)(p2 >> 32)) * x2);
        atomicAdd(&acc[(unsigned int)p3 & (CHUNK - 1)], __uint_as_float((unsigned int)(p3 >> 32)) * x3);
    }
    for (; i < s1; i += BSA) {
        unsigned long long p = payload[i];
        float xv = xd[((unsigned int)p >> LOG_CHUNK) & 0xFFFFFFu];
        atomicAdd(&acc[(unsigned int)p & (CHUNK - 1)], __uint_as_float((unsigned int)(p >> 32)) * xv);
    }
    __syncthreads();
    int n = b * CHUNK + t;
    if (t < CHUNK && n < N) {
        float dv = dinv[n];
        float sv = dv * (acc[t] + xd[n]);        // + self-loop dv*dv*x[n]
        float g = 0.0f;
#pragma unroll
        for (int f = 0; f < 16; ++f) {
            float h = fmaxf(sv * W1[f] + b1[f], 0.0f);     // relu(layer1)
            g += h * (W2[2 * f + 1] - W2[2 * f + 0]);      // gamma = g1-g0
        }
        gd[n] = dv * g;                          // pre-scaled for layer 2
    }
}

__global__ __launch_bounds__(BSA) void d_out_kernel(
    const unsigned long long* __restrict__ payload,
    const unsigned int* __restrict__ start,
    const float* __restrict__ dinv,
    const float* __restrict__ gd,
    const float* __restrict__ b2,    // [2]
    float* __restrict__ out, int N) {
    __shared__ float acc[CHUNK];
    const int b = blockIdx.x, t = threadIdx.x;
    if (t < CHUNK) acc[t] = 0.0f;
    __syncthreads();
    const unsigned int s0 = start[b], s1 = start[b + 1];
    unsigned int i = s0 + t;
    for (; i + 3u * BSA < s1; i += 4u * BSA) {
        unsigned long long p0 = payload[i],           p1 = payload[i + BSA];
        unsigned long long p2 = payload[i + 2 * BSA], p3 = payload[i + 3 * BSA];
        float g0 = gd[((unsigned int)p0 >> LOG_CHUNK) & 0xFFFFFFu];
        float g1 = gd[((unsigned int)p1 >> LOG_CHUNK) & 0xFFFFFFu];
        float g2 = gd[((unsigned int)p2 >> LOG_CHUNK) & 0xFFFFFFu];
        float g3 = gd[((unsigned int)p3 >> LOG_CHUNK) & 0xFFFFFFu];
        atomicAdd(&acc[(unsigned int)p0 & (CHUNK - 1)], __uint_as_float((unsigned int)(p0 >> 32)) * g0);
        atomicAdd(&acc[(unsigned int)p1 & (CHUNK - 1)], __uint_as_float((unsigned int)(p1 >> 32)) * g1);
        atomicAdd(&acc[(unsigned int)p2 & (CHUNK - 1)], __uint_as_float((unsigned int)(p2 >> 32)) * g2);
        atomicAdd(&acc[(unsigned int)p3 & (CHUNK - 1)], __uint_as_float((unsigned int)(p3 >> 32)) * g3);
    }
    for (; i < s1; i += BSA) {
        unsigned long long p = payload[i];
        float gv = gd[((unsigned int)p >> LOG_CHUNK) & 0xFFFFFFu];
        atomicAdd(&acc[(unsigned int)p & (CHUNK - 1)], __uint_as_float((unsigned int)(p >> 32)) * gv);
    }
    __syncthreads();
    int n = b * CHUNK + t;
    if (t < CHUNK && n < N) {
        float dv = dinv[n];
        float d = dv * (acc[t] + gd[n]) + (b2[1] - b2[0]);
        float lse = fmaxf(d, 0.0f) + log1pf(expf(-fabsf(d)));   // log(1+e^d)
        out[2 * n + 0] = -lse;
        out[2 * n + 1] = d - lse;
    }
}

// ======================= fallback: R3 global-atomic path =======================

static constexpr int BLOCK = 256;

__global__ void zero_kernel(float* __restrict__ a, float* __restrict__ b, int n2) {
    int i = blockIdx.x * blockDim.x + threadIdx.x;
    if (i < n2) { a[i] = 0.0f; b[i] = 0.0f; }
}
__global__ void deg_kernel(const int* __restrict__ dst, const float* __restrict__ w,
                           float* __restrict__ deg, int E) {
    int e = blockIdx.x * blockDim.x + threadIdx.x;
    if (e < E) atomicAdd(&deg[dst[e]], w[e]);
}
__global__ void dinv_kernel(float* __restrict__ deg, int N) {
    int n = blockIdx.x * blockDim.x + threadIdx.x;
    if (n < N) {
        float d = deg[n] + 1.0f;
        deg[n] = (d > 0.0f) ? rsqrtf(d) : 0.0f;
    }
}
__global__ void s_kernel(const int* __restrict__ src, const int* __restrict__ dst,
                         const float* __restrict__ w, const float* __restrict__ dinv,
                         const float* __restrict__ x, float* __restrict__ s, int E) {
    int e = blockIdx.x * blockDim.x + threadIdx.x;
    if (e < E) {
        int si = src[e], di = dst[e];
        atomicAdd(&s[di], dinv[si] * w[e] * dinv[di] * x[si]);
    }
}
__global__ void g_kernel(const float* __restrict__ s, const float* __restrict__ dinv,
                         const float* __restrict__ x, const float* __restrict__ W1,
                         const float* __restrict__ b1, const float* __restrict__ W2,
                         float2* __restrict__ g, int N) {
    int n = blockIdx.x * blockDim.x + threadIdx.x;
    if (n < N) {
        float dv = dinv[n];
        float sv = s[n] + dv * dv * x[n];
        float g0 = 0.0f, g1 = 0.0f;
#pragma unroll
        for (int f = 0; f < 16; ++f) {
            float h = fmaxf(sv * W1[f] + b1[f], 0.0f);
            g0 += h * W2[2 * f + 0];
            g1 += h * W2[2 * f + 1];
        }
        g[n] = make_float2(g0, g1);
    }
}
__global__ void agg2_kernel(const int* __restrict__ src, const int* __restrict__ dst,
                            const float* __restrict__ w, const float* __restrict__ dinv,
                            const float2* __restrict__ g, float* __restrict__ agg, int E) {
    int e = blockIdx.x * blockDim.x + threadIdx.x;
    if (e < E) {
        int si = src[e], di = dst[e];
        float norm = dinv[si] * w[e] * dinv[di];
        float2 gv = g[si];
        atomicAdd(&agg[2 * di + 0], norm * gv.x);
        atomicAdd(&agg[2 * di + 1], norm * gv.y);
    }
}
__global__ void out_kernel(float* __restrict__ out, const float* __restrict__ dinv,
                           const float2* __restrict__ g, const float* __restrict__ b2, int N) {
    int n = blockIdx.x * blockDim.x + threadIdx.x;
    if (n < N) {
        float dv2 = dinv[n] * dinv[n];
        float2 gv = g[n];
        float a0 = out[2 * n + 0] + dv2 * gv.x + b2[0];
        float a1 = out[2 * n + 1] + dv2 * gv.y + b2[1];
        float m = fmaxf(a0, a1);
        float lse = m + logf(expf(a0 - m) + expf(a1 - m));
        out[2 * n + 0] = a0 - lse;
        out[2 * n + 1] = a1 - lse;
    }
}

// ======================= launch =======================

extern "C" void kernel_launch(void* const* d_in, const int* in_sizes, int n_in,
                              void* d_out, int out_size, void* d_ws, size_t ws_size,
                              hipStream_t stream) {
    const float* x  = (const float*)d_in[0];
    const int*   ei = (const int*)d_in[1];     // [2, E] delivered as int32
    const float* w  = (const float*)d_in[2];
    const float* W1 = (const float*)d_in[3];
    const float* b1 = (const float*)d_in[4];
    const float* W2 = (const float*)d_in[5];
    const float* b2 = (const float*)d_in[6];
    float* out = (float*)d_out;

    const int N = in_sizes[0];
    const int E = in_sizes[2];
    const int* src = ei;
    const int* dst = ei + E;

    const int nb = (N + CHUNK - 1) / CHUNK;    // 391

    // ws layout: payload | cnt | start | cursor | dinv | xd | gd
    size_t off = 0;
    size_t payload_off = off;  off += (size_t)E * 8;
    size_t cnt_off     = off;  off += (size_t)nb * 4;
    size_t start_off   = off;  off += (size_t)(nb + 1) * 4;
    size_t cursor_off  = off;  off += (size_t)nb * 4;
    off = (off + 7) & ~(size_t)7;
    size_t dinv_off    = off;  off += (size_t)N * 4;
    size_t xd_off      = off;  off += (size_t)N * 4;
    size_t gd_off      = off;  off += (size_t)N * 4;
    const size_t required = off;

    if (nb <= MAXNB && ws_size >= required) {
        char* wsb = (char*)d_ws;
        unsigned long long* payload = (unsigned long long*)(wsb + payload_off);
        unsigned int* cnt    = (unsigned int*)(wsb + cnt_off);
        unsigned int* startp = (unsigned int*)(wsb + start_off);
        unsigned int* cursor = (unsigned int*)(wsb + cursor_off);
        float* dinv = (float*)(wsb + dinv_off);
        float* xd   = (float*)(wsb + xd_off);
        float* gd   = (float*)(wsb + gd_off);

        const int gridT = (E + EPT - 1) / EPT;     // 261

        zero_cnt_kernel<<<1,     BS,  0, stream>>>(cnt, nb);
        hist_kernel    <<<gridT, BS,  0, stream>>>(dst, cnt, E, nb);
        scan_kernel    <<<1,     512, 0, stream>>>(cnt, startp, cursor, nb);
        place_kernel   <<<gridT, BS,  0, stream>>>(src, dst, w, cursor, payload, E, nb);
        deg_dinv_kernel<<<nb,    BSA, 0, stream>>>(payload, startp, x, dinv, xd, N);
        s_gamma_kernel <<<nb,    BSA, 0, stream>>>(payload, startp, dinv, xd, W1, b1, W2, gd, N);
        d_out_kernel   <<<nb,    BSA, 0, stream>>>(payload, startp, dinv, gd, b2, out, N);
    } else {
        // R3 fallback: global-atomic path (needs 4N floats of ws)
        float*  ws   = (float*)d_ws;
        float*  dinv = ws;
        float*  s    = ws + (size_t)N;
        float2* g    = (float2*)(ws + (size_t)2 * N);
        const int gridE  = (E + BLOCK - 1) / BLOCK;
        const int gridN  = (N + BLOCK - 1) / BLOCK;
        const int gridN2 = (2 * N + BLOCK - 1) / BLOCK;
        zero_kernel<<<gridN2, BLOCK, 0, stream>>>(ws, out, 2 * N);
        deg_kernel <<<gridE,  BLOCK, 0, stream>>>(dst, w, dinv, E);
        dinv_kernel<<<gridN,  BLOCK, 0, stream>>>(dinv, N);
        s_kernel   <<<gridE,  BLOCK, 0, stream>>>(src, dst, w, dinv, x, s, E);
        g_kernel   <<<gridN,  BLOCK, 0, stream>>>(s, dinv, x, W1, b1, W2, g, N);
        agg2_kernel<<<gridE,  BLOCK, 0, stream>>>(src, dst, w, dinv, g, out, E);
        out_kernel <<<gridN,  BLOCK, 0, stream>>>(out, dinv, g, b2, N);
    }
}